// Round 12
// baseline (16.131 us; speedup 1.0000x reference)
//
#include <hip/hip_runtime.h>

#define B_   256
#define P_   1152
#define J_   10
#define NT   384      // 6 waves
#define NWV  6
#define PW   192      // p-rows per wave
#define XSTR 1176     // xT row stride (shorts)
#define LOG2E 1.44269504088896340736f

typedef __attribute__((ext_vector_type(8))) short short8;
typedef __attribute__((ext_vector_type(4))) float f32x4;

union Frag { short8 s; unsigned u[4]; };

__device__ __forceinline__ unsigned pk_bf16(float lo, float hi) {
  unsigned r;
  asm("v_cvt_pk_bf16_f32 %0, %1, %2" : "=v"(r) : "v"(lo), "v"(hi));
  return r;
}
__device__ __forceinline__ float bf_lo(unsigned u){ return __builtin_bit_cast(float, u << 16); }
__device__ __forceinline__ float bf_hi(unsigned u){ return __builtin_bit_cast(float, u & 0xffff0000u); }

template<int CTRL>
__device__ __forceinline__ float dpp_add(float v) {
  int s = __builtin_amdgcn_update_dpp(0, __builtin_bit_cast(int, v), CTRL, 0xF, 0xF, true);
  return v + __builtin_bit_cast(float, s);
}
__device__ __forceinline__ float rsum_shr(float v) {  // lane15 of each 16-row gets sum
  v = dpp_add<0x111>(v); v = dpp_add<0x112>(v);
  v = dpp_add<0x114>(v); v = dpp_add<0x118>(v);
  return v;
}
__device__ __forceinline__ float rsum_ror(float v) {  // all 16 lanes get the sum
  v = dpp_add<0x121>(v); v = dpp_add<0x122>(v);
  v = dpp_add<0x124>(v); v = dpp_add<0x128>(v);
  return v;
}

// LDS (dynamic, 72736 B):
//  xT    short[9][1176]    @0      x^T bf16 (rows 0-7 = x[k][p], row 8 = ones)
//  eL    short[6][16][200] @21168  per-wave e^T (bf16) [j][p_loc]
//  Wt    float[1440]       @59568  Wt[(j*8+k)*18+d] = W[j][d][k]
//  ypart float[6][272]     @65328  per-wave y tiles [16j][17]
//  red   float[92]         @71856  y[j*8+k], S at 80+j
//  Zacc  float[128]        @72224  cumulative z*log2e (80..127 zero pad)
__global__ __launch_bounds__(NT, 2) void caps_kernel(const float* __restrict__ x,
                                                     const float* __restrict__ Wg,
                                                     float* __restrict__ out) {
  extern __shared__ char smc[];
  short* xT    = (short*)smc;
  short* eL    = (short*)(smc + 21168);
  float* Wt    = (float*)(smc + 59568);
  float* ypart = (float*)(smc + 65328);
  float* red   = (float*)(smc + 71856);
  float* Zacc  = (float*)(smc + 72224);

  const int tid  = threadIdx.x;
  const int w    = tid >> 6;
  const int lane = tid & 63;
  const int b    = blockIdx.x;
  const int jl   = lane & 15;     // 16-col index
  const int g    = lane >> 4;     // 4-group

  const float* xb = x + (size_t)b * (P_ * 8);

  // ---- preamble (single pass over x, one barrier): Wt, Zacc, Ax + fused xT scatter ----
  for (int t = tid; t < 1280; t += NT) {
    const int j = t >> 7, d = (t >> 3) & 15, k = t & 7;
    Wt[(j * 8 + k) * 18 + d] = Wg[t];
  }
  if (tid < 128) Zacc[tid] = 0.f;

  Frag Ax[12];
  {
    const bool lop = (g & 1);
    #pragma unroll
    for (int t = 0; t < 12; ++t) {
      const int p = w * PW + t * 16 + jl;
      const float* xr = xb + (size_t)p * 8;
      const float4 a4 = ((const float4*)xr)[0];
      const float4 b4 = ((const float4*)xr)[1];
      const float xv[8] = {a4.x, a4.y, a4.z, a4.w, b4.x, b4.y, b4.z, b4.w};
      #pragma unroll
      for (int q = 0; q < 4; ++q) {
        unsigned h = pk_bf16(xv[2 * q], xv[2 * q + 1]);
        if (lop) {
          const float l0 = xv[2 * q]     - bf_lo(h);
          const float l1 = xv[2 * q + 1] - bf_hi(h);
          h = pk_bf16(l0, l1);
        }
        Ax[t].u[q] = h;
      }
      if (g == 0) {
        #pragma unroll
        for (int k = 0; k < 4; ++k)
          xT[k * XSTR + p] = (short)(pk_bf16(xv[k], xv[k]) & 0xffff);
      } else if (g == 1) {
        #pragma unroll
        for (int k = 4; k < 8; ++k)
          xT[k * XSTR + p] = (short)(pk_bf16(xv[k], xv[k]) & 0xffff);
      } else if (g == 2) {
        xT[8 * XSTR + p] = (short)0x3F80;
      }
    }
  }
  __syncthreads();

  // B-frags for y-MFMA (iteration-invariant): col jl = feature k, 8 consecutive p.
  // jl in 9..15 reads past xT (stale bytes) -> pollutes only ignored D columns.
  Frag Bx[6];
  #pragma unroll
  for (int tp = 0; tp < 6; ++tp)
    Bx[tp].s = *(const short8*)&xT[jl * XSTR + w * PW + tp * 32 + g * 8];

  Frag ones;
  #pragma unroll
  for (int q = 0; q < 4; ++q) ones.u[q] = 0x3F803F80u;

  short* eW = eL + w * 3200;

  for (int it = 0; it < 3; ++it) {
    // ---------------- Y phase: b-MFMA -> exp2 -> e-write; then af-read -> y-MFMA ----------------
    f32x4 yC0 = {0.f, 0.f, 0.f, 0.f};
    f32x4 yC1 = {0.f, 0.f, 0.f, 0.f};
    if (it == 0) {                        // e == 1; split accumulator chains
      #pragma unroll
      for (int tp = 0; tp < 6; tp += 2) {
        yC0 = __builtin_amdgcn_mfma_f32_16x16x32_bf16(ones.s, Bx[tp].s,     yC0, 0, 0, 0);
        yC1 = __builtin_amdgcn_mfma_f32_16x16x32_bf16(ones.s, Bx[tp + 1].s, yC1, 0, 0, 0);
      }
    } else {
      Frag zf;                            // B-frag of Z: g 0,1 = Zh, g 2,3 = Zl
      {
        const float4 za = *(const float4*)&Zacc[jl * 8];
        const float4 zb = *(const float4*)&Zacc[jl * 8 + 4];
        const float zv[8] = {za.x, za.y, za.z, za.w, zb.x, zb.y, zb.z, zb.w};
        #pragma unroll
        for (int q = 0; q < 4; ++q) {
          unsigned h = pk_bf16(zv[2 * q], zv[2 * q + 1]);
          if (g >= 2) {
            const float l0 = zv[2 * q]     - bf_lo(h);
            const float l1 = zv[2 * q + 1] - bf_hi(h);
            h = pk_bf16(l0, l1);
          }
          zf.u[q] = h;
        }
      }
      #pragma unroll
      for (int t = 0; t < 12; ++t) {      // b = x.Z exact via hi/lo K-packing
        f32x4 bC = {0.f, 0.f, 0.f, 0.f};
        bC = __builtin_amdgcn_mfma_f32_16x16x32_bf16(Ax[t].s, zf.s, bC, 0, 0, 0);
        const float e0 = exp2f(bC[0]), e1 = exp2f(bC[1]);
        const float e2 = exp2f(bC[2]), e3 = exp2f(bC[3]);
        *(uint2*)&eW[jl * 200 + t * 16 + g * 4] =
            make_uint2(pk_bf16(e0, e1), pk_bf16(e2, e3));
      }
      #pragma unroll
      for (int tp = 0; tp < 6; tp += 2) { // y[j][k] (+ S at col 8), split chains
        Frag af0, af1;
        af0.s = *(const short8*)&eW[jl * 200 + tp * 32 + g * 8];
        af1.s = *(const short8*)&eW[jl * 200 + (tp + 1) * 32 + g * 8];
        yC0 = __builtin_amdgcn_mfma_f32_16x16x32_bf16(af0.s, Bx[tp].s,     yC0, 0, 0, 0);
        yC1 = __builtin_amdgcn_mfma_f32_16x16x32_bf16(af1.s, Bx[tp + 1].s, yC1, 0, 0, 0);
      }
    }
    #pragma unroll
    for (int r = 0; r < 4; ++r)           // D[j=g*4+r][k=jl]
      ypart[w * 272 + (g * 4 + r) * 17 + jl] = yC0[r] + yC1[r];
    __syncthreads();

    // ---- M (tid<160, one stage): combine -> s -> squash -> v -> (out | z -> Zacc) ----
    // red writers (d<9) and readers of each j-group are the same 16-lane group
    // of the same wave -> in-wave LDS ordering (lgkmcnt) suffices, no barrier.
    if (tid < 160) {
      const int j = tid >> 4, d = tid & 15;
      if (d < 9) {
        float s6 = 0.f;
        #pragma unroll
        for (int w6 = 0; w6 < NWV; ++w6) s6 += ypart[w6 * 272 + j * 17 + d];
        red[(d < 8) ? (j * 8 + d) : (80 + j)] = s6;
      }
      float wk[8];
      #pragma unroll
      for (int k = 0; k < 8; ++k) wk[k] = Wt[(j * 8 + k) * 18 + d];
      float s = 0.f;
      #pragma unroll
      for (int k = 0; k < 8; ++k) s = fmaf(wk[k], red[j * 8 + k], s);
      s /= red[80 + j];
      const float sq = rsum_ror(s * s);
      const float scal = sq / ((1.0f + sq) * sqrtf(sq + 1e-9f));
      const float v = s * scal;
      if (it == 2) {
        out[b * 160 + tid] = v;
      } else {
        float zk[8];
        #pragma unroll
        for (int k = 0; k < 8; ++k) zk[k] = rsum_shr(wk[k] * v);
        if (d == 15) {
          #pragma unroll
          for (int k = 0; k < 8; ++k)
            Zacc[j * 8 + k] = fmaf(zk[k], LOG2E, Zacc[j * 8 + k]);
        }
      }
    }
    if (it < 2) __syncthreads();
  }
}

extern "C" void kernel_launch(void* const* d_in, const int* in_sizes, int n_in,
                              void* d_out, int out_size, void* d_ws, size_t ws_size,
                              hipStream_t stream) {
  (void)in_sizes; (void)n_in; (void)out_size; (void)d_ws; (void)ws_size;
  const float* x = (const float*)d_in[0];
  const float* W = (const float*)d_in[1];
  float* out = (float*)d_out;

  const size_t smem = 72736;
  (void)hipFuncSetAttribute(reinterpret_cast<const void*>(caps_kernel),
                            hipFuncAttributeMaxDynamicSharedMemorySize, (int)smem);
  caps_kernel<<<B_, NT, smem, stream>>>(x, W, out);
}

// Round 13
// 15.373 us; speedup vs baseline: 1.0493x; 1.0493x over previous
//
#include <hip/hip_runtime.h>

#define B_   256
#define P_   1152
#define J_   10
#define NT   384      // 6 waves
#define NWV  6
#define PW   192      // p-rows per wave
#define LOG2E 1.44269504088896340736f

typedef __attribute__((ext_vector_type(8))) short short8;
typedef __attribute__((ext_vector_type(4))) float f32x4;

union Frag { short8 s; unsigned u[4]; };

__device__ __forceinline__ unsigned pk_bf16(float lo, float hi) {
  unsigned r;
  asm("v_cvt_pk_bf16_f32 %0, %1, %2" : "=v"(r) : "v"(lo), "v"(hi));
  return r;
}
__device__ __forceinline__ float bf_lo(unsigned u){ return __builtin_bit_cast(float, u << 16); }
__device__ __forceinline__ float bf_hi(unsigned u){ return __builtin_bit_cast(float, u & 0xffff0000u); }

template<int CTRL>
__device__ __forceinline__ float dpp_add(float v) {
  int s = __builtin_amdgcn_update_dpp(0, __builtin_bit_cast(int, v), CTRL, 0xF, 0xF, true);
  return v + __builtin_bit_cast(float, s);
}
__device__ __forceinline__ float rsum_shr(float v) {  // lane15 of each 16-row gets sum
  v = dpp_add<0x111>(v); v = dpp_add<0x112>(v);
  v = dpp_add<0x114>(v); v = dpp_add<0x118>(v);
  return v;
}
__device__ __forceinline__ float rsum_ror(float v) {  // all 16 lanes get the sum
  v = dpp_add<0x121>(v); v = dpp_add<0x122>(v);
  v = dpp_add<0x124>(v); v = dpp_add<0x128>(v);
  return v;
}

// LDS (dynamic, 88944 B):
//  xT    short[16][1168] @0       x^T bf16 (rows 0-7 = x[k][p], row 8 = ones)
//  eL    short[6][16][200] @37376 per-wave e^T (bf16) [j][p_loc]
//  Wt    float[80*18]   @75776    Wt[(j*8+k)*18+d] = W[j][d][k]
//  ypart float[6][272]  @81536    per-wave y tiles [16j][17]
//  red   float[92]      @88064    y[j*8+k], S at 80+j
//  Zacc  float[128]     @88432    cumulative z*log2e (rows 80-127 zero)
__global__ __launch_bounds__(NT, 2) void caps_kernel(const float* __restrict__ x,
                                                     const float* __restrict__ Wg,
                                                     float* __restrict__ out) {
  extern __shared__ char smc[];
  short* xT    = (short*)smc;
  short* eL    = (short*)(smc + 37376);
  float* Wt    = (float*)(smc + 75776);
  float* ypart = (float*)(smc + 81536);
  float* red   = (float*)(smc + 88064);
  float* Zacc  = (float*)(smc + 88432);

  const int tid  = threadIdx.x;
  const int w    = tid >> 6;
  const int lane = tid & 63;
  const int b    = blockIdx.x;
  const int jl   = lane & 15;     // 16-col index
  const int g    = lane >> 4;     // 4-group

  // ---- phase 0: zero xT + Zacc ----
  {
    float4* xTf = (float4*)xT;
    const float4 z4 = make_float4(0.f, 0.f, 0.f, 0.f);
    for (int i = tid; i < 2336; i += NT) xTf[i] = z4;
    if (tid < 128) Zacc[tid] = 0.f;
  }
  __syncthreads();

  // ---- phase 1: fill xT (bf16 transposed + ones row), Wt; Ax from global ----
  const float* xb = x + (size_t)b * (P_ * 8);
  for (int i = tid; i < 2304; i += NT) {
    float4 v4 = ((const float4*)xb)[i];
    const int p = i >> 1, k0 = (i & 1) * 4;
    xT[(k0 + 0) * 1168 + p] = (short)(pk_bf16(v4.x, v4.x) & 0xffff);
    xT[(k0 + 1) * 1168 + p] = (short)(pk_bf16(v4.y, v4.y) & 0xffff);
    xT[(k0 + 2) * 1168 + p] = (short)(pk_bf16(v4.z, v4.z) & 0xffff);
    xT[(k0 + 3) * 1168 + p] = (short)(pk_bf16(v4.w, v4.w) & 0xffff);
  }
  for (int p = tid; p < P_; p += NT) xT[8 * 1168 + p] = (short)0x3F80;
  for (int t = tid; t < 1280; t += NT) {
    const int j = t >> 7, d = (t >> 3) & 15, k = t & 7;
    Wt[(j * 8 + k) * 18 + d] = Wg[t];
  }

  Frag Ax[12];
  {
    const bool lop = (g & 1);
    #pragma unroll
    for (int t = 0; t < 12; ++t) {
      const float* xr = xb + ((size_t)(w * PW + t * 16 + jl)) * 8;
      const float4 a4 = ((const float4*)xr)[0];
      const float4 b4 = ((const float4*)xr)[1];
      const float xv[8] = {a4.x, a4.y, a4.z, a4.w, b4.x, b4.y, b4.z, b4.w};
      #pragma unroll
      for (int q = 0; q < 4; ++q) {
        unsigned h = pk_bf16(xv[2 * q], xv[2 * q + 1]);
        if (lop) {
          const float l0 = xv[2 * q]     - bf_lo(h);
          const float l1 = xv[2 * q + 1] - bf_hi(h);
          h = pk_bf16(l0, l1);
        }
        Ax[t].u[q] = h;
      }
    }
  }
  __syncthreads();

  // B-frags for y-MFMA (iteration-invariant)
  Frag Bx[6];
  #pragma unroll
  for (int tp = 0; tp < 6; ++tp)
    Bx[tp].s = *(const short8*)&xT[jl * 1168 + w * PW + tp * 32 + g * 8];

  Frag ones;
  #pragma unroll
  for (int q = 0; q < 4; ++q) ones.u[q] = 0x3F803F80u;

  short* eW = eL + w * 3200;

  for (int it = 0; it < 3; ++it) {
    // ---------------- Y phase: b-MFMA -> exp2 -> e-write; then af-read -> y-MFMA ----------------
    f32x4 yC0 = {0.f, 0.f, 0.f, 0.f};
    f32x4 yC1 = {0.f, 0.f, 0.f, 0.f};
    if (it == 0) {                        // e == 1; split accumulator chains
      #pragma unroll
      for (int tp = 0; tp < 6; tp += 2) {
        yC0 = __builtin_amdgcn_mfma_f32_16x16x32_bf16(ones.s, Bx[tp].s,     yC0, 0, 0, 0);
        yC1 = __builtin_amdgcn_mfma_f32_16x16x32_bf16(ones.s, Bx[tp + 1].s, yC1, 0, 0, 0);
      }
    } else {
      Frag zf;                            // B-frag of Z: g 0,1 = Zh, g 2,3 = Zl
      {
        const float4 za = *(const float4*)&Zacc[jl * 8];
        const float4 zb = *(const float4*)&Zacc[jl * 8 + 4];
        const float zv[8] = {za.x, za.y, za.z, za.w, zb.x, zb.y, zb.z, zb.w};
        #pragma unroll
        for (int q = 0; q < 4; ++q) {
          unsigned h = pk_bf16(zv[2 * q], zv[2 * q + 1]);
          if (g >= 2) {
            const float l0 = zv[2 * q]     - bf_lo(h);
            const float l1 = zv[2 * q + 1] - bf_hi(h);
            h = pk_bf16(l0, l1);
          }
          zf.u[q] = h;
        }
      }
      #pragma unroll
      for (int t = 0; t < 12; ++t) {      // b = x.Z exact via hi/lo K-packing
        f32x4 bC = {0.f, 0.f, 0.f, 0.f};
        bC = __builtin_amdgcn_mfma_f32_16x16x32_bf16(Ax[t].s, zf.s, bC, 0, 0, 0);
        const float e0 = exp2f(bC[0]), e1 = exp2f(bC[1]);
        const float e2 = exp2f(bC[2]), e3 = exp2f(bC[3]);
        *(uint2*)&eW[jl * 200 + t * 16 + g * 4] =
            make_uint2(pk_bf16(e0, e1), pk_bf16(e2, e3));
      }
      #pragma unroll
      for (int tp = 0; tp < 6; tp += 2) { // y[j][k] (+ S at col 8), split chains
        Frag af0, af1;
        af0.s = *(const short8*)&eW[jl * 200 + tp * 32 + g * 8];
        af1.s = *(const short8*)&eW[jl * 200 + (tp + 1) * 32 + g * 8];
        yC0 = __builtin_amdgcn_mfma_f32_16x16x32_bf16(af0.s, Bx[tp].s,     yC0, 0, 0, 0);
        yC1 = __builtin_amdgcn_mfma_f32_16x16x32_bf16(af1.s, Bx[tp + 1].s, yC1, 0, 0, 0);
      }
    }
    #pragma unroll
    for (int r = 0; r < 4; ++r)           // D[j=g*4+r][k=jl]
      ypart[w * 272 + (g * 4 + r) * 17 + jl] = yC0[r] + yC1[r];
    __syncthreads();

    // ---- M (tid<160, one stage): combine -> s -> squash -> v -> (out | z -> Zacc) ----
    // red writers (d<9) and readers of each j-group are the same 16-lane group
    // of the same wave -> in-wave LDS ordering (lgkmcnt) suffices, no barrier.
    if (tid < 160) {
      const int j = tid >> 4, d = tid & 15;
      if (d < 9) {
        float s6 = 0.f;
        #pragma unroll
        for (int w6 = 0; w6 < NWV; ++w6) s6 += ypart[w6 * 272 + j * 17 + d];
        red[(d < 8) ? (j * 8 + d) : (80 + j)] = s6;
      }
      float wk[8];
      #pragma unroll
      for (int k = 0; k < 8; ++k) wk[k] = Wt[(j * 8 + k) * 18 + d];
      float s = 0.f;
      #pragma unroll
      for (int k = 0; k < 8; ++k) s = fmaf(wk[k], red[j * 8 + k], s);
      s /= red[80 + j];
      const float sq = rsum_ror(s * s);
      const float scal = sq / ((1.0f + sq) * sqrtf(sq + 1e-9f));
      const float v = s * scal;
      if (it == 2) {
        out[b * 160 + tid] = v;
      } else {
        float zk[8];
        #pragma unroll
        for (int k = 0; k < 8; ++k) zk[k] = rsum_shr(wk[k] * v);
        if (d == 15) {
          #pragma unroll
          for (int k = 0; k < 8; ++k)
            Zacc[j * 8 + k] = fmaf(zk[k], LOG2E, Zacc[j * 8 + k]);
        }
      }
    }
    if (it < 2) __syncthreads();
  }
}

extern "C" void kernel_launch(void* const* d_in, const int* in_sizes, int n_in,
                              void* d_out, int out_size, void* d_ws, size_t ws_size,
                              hipStream_t stream) {
  (void)in_sizes; (void)n_in; (void)out_size; (void)d_ws; (void)ws_size;
  const float* x = (const float*)d_in[0];
  const float* W = (const float*)d_in[1];
  float* out = (float*)d_out;

  const size_t smem = 88944;
  (void)hipFuncSetAttribute(reinterpret_cast<const void*>(caps_kernel),
                            hipFuncAttributeMaxDynamicSharedMemorySize, (int)smem);
  caps_kernel<<<B_, NT, smem, stream>>>(x, W, out);
}

// Round 15
// 13.531 us; speedup vs baseline: 1.1921x; 1.1362x over previous
//
#include <hip/hip_runtime.h>

#define B_   256
#define P_   1152
#define J_   10
#define NT   384      // 6 waves
#define NWV  6
#define PW   192      // p-rows per wave
#define LOG2E 1.44269504088896340736f

typedef __attribute__((ext_vector_type(8))) short short8;
typedef __attribute__((ext_vector_type(4))) float f32x4;

union Frag { short8 s; unsigned u[4]; };

__device__ __forceinline__ unsigned pk_bf16(float lo, float hi) {
  unsigned r;
  asm("v_cvt_pk_bf16_f32 %0, %1, %2" : "=v"(r) : "v"(lo), "v"(hi));
  return r;
}
__device__ __forceinline__ float bf_lo(unsigned u){ return __builtin_bit_cast(float, u << 16); }
__device__ __forceinline__ float bf_hi(unsigned u){ return __builtin_bit_cast(float, u & 0xffff0000u); }

// raw hardware transcendentals via BUILTINS (backend-emitted: hazards handled,
// unlike the R14 inline-asm which hit the gfx9 trans-op wait-state hazard)
__device__ __forceinline__ float fexp2(float x) { return __builtin_amdgcn_exp2f(x); }
__device__ __forceinline__ float frcp (float x) { return __builtin_amdgcn_rcpf(x); }
__device__ __forceinline__ float frsq (float x) { return __builtin_amdgcn_rsqf(x); }

template<int CTRL>
__device__ __forceinline__ float dpp_add(float v) {
  int s = __builtin_amdgcn_update_dpp(0, __builtin_bit_cast(int, v), CTRL, 0xF, 0xF, true);
  return v + __builtin_bit_cast(float, s);
}
__device__ __forceinline__ float rsum_shr(float v) {  // lane15 of each 16-row gets sum
  v = dpp_add<0x111>(v); v = dpp_add<0x112>(v);
  v = dpp_add<0x114>(v); v = dpp_add<0x118>(v);
  return v;
}
__device__ __forceinline__ float rsum_ror(float v) {  // all 16 lanes get the sum
  v = dpp_add<0x121>(v); v = dpp_add<0x122>(v);
  v = dpp_add<0x124>(v); v = dpp_add<0x128>(v);
  return v;
}

// LDS (dynamic, 88944 B) — identical to R13:
//  xT    short[16][1168] @0       x^T bf16 (rows 0-7 = x[k][p], row 8 = ones)
//  eL    short[6][16][200] @37376 per-wave e^T (bf16) [j][p_loc]
//  Wt    float[80*18]   @75776    Wt[(j*8+k)*18+d] = W[j][d][k]
//  ypart float[6][272]  @81536    per-wave y tiles [16j][17]
//  red   float[92]      @88064    y[j*8+k], S at 80+j
//  Zacc  float[128]     @88432    cumulative z*log2e (rows 80-127 zero)
__global__ __launch_bounds__(NT, 2) void caps_kernel(const float* __restrict__ x,
                                                     const float* __restrict__ Wg,
                                                     float* __restrict__ out) {
  extern __shared__ char smc[];
  short* xT    = (short*)smc;
  short* eL    = (short*)(smc + 37376);
  float* Wt    = (float*)(smc + 75776);
  float* ypart = (float*)(smc + 81536);
  float* red   = (float*)(smc + 88064);
  float* Zacc  = (float*)(smc + 88432);

  const int tid  = threadIdx.x;
  const int w    = tid >> 6;
  const int lane = tid & 63;
  const int b    = blockIdx.x;
  const int jl   = lane & 15;     // 16-col index
  const int g    = lane >> 4;     // 4-group

  // ---- phase 0: zero xT + Zacc ----
  {
    float4* xTf = (float4*)xT;
    const float4 z4 = make_float4(0.f, 0.f, 0.f, 0.f);
    for (int i = tid; i < 2336; i += NT) xTf[i] = z4;
    if (tid < 128) Zacc[tid] = 0.f;
  }
  __syncthreads();

  // ---- phase 1: fill xT (bf16 transposed + ones row), Wt; Ax from global ----
  const float* xb = x + (size_t)b * (P_ * 8);
  for (int i = tid; i < 2304; i += NT) {
    float4 v4 = ((const float4*)xb)[i];
    const int p = i >> 1, k0 = (i & 1) * 4;
    xT[(k0 + 0) * 1168 + p] = (short)(pk_bf16(v4.x, v4.x) & 0xffff);
    xT[(k0 + 1) * 1168 + p] = (short)(pk_bf16(v4.y, v4.y) & 0xffff);
    xT[(k0 + 2) * 1168 + p] = (short)(pk_bf16(v4.z, v4.z) & 0xffff);
    xT[(k0 + 3) * 1168 + p] = (short)(pk_bf16(v4.w, v4.w) & 0xffff);
  }
  for (int p = tid; p < P_; p += NT) xT[8 * 1168 + p] = (short)0x3F80;
  for (int t = tid; t < 1280; t += NT) {
    const int j = t >> 7, d = (t >> 3) & 15, k = t & 7;
    Wt[(j * 8 + k) * 18 + d] = Wg[t];
  }

  Frag Ax[12];
  {
    const bool lop = (g & 1);
    #pragma unroll
    for (int t = 0; t < 12; ++t) {
      const float* xr = xb + ((size_t)(w * PW + t * 16 + jl)) * 8;
      const float4 a4 = ((const float4*)xr)[0];
      const float4 b4 = ((const float4*)xr)[1];
      const float xv[8] = {a4.x, a4.y, a4.z, a4.w, b4.x, b4.y, b4.z, b4.w};
      #pragma unroll
      for (int q = 0; q < 4; ++q) {
        unsigned h = pk_bf16(xv[2 * q], xv[2 * q + 1]);
        if (lop) {
          const float l0 = xv[2 * q]     - bf_lo(h);
          const float l1 = xv[2 * q + 1] - bf_hi(h);
          h = pk_bf16(l0, l1);
        }
        Ax[t].u[q] = h;
      }
    }
  }
  __syncthreads();

  // B-frags for y-MFMA (iteration-invariant)
  Frag Bx[6];
  #pragma unroll
  for (int tp = 0; tp < 6; ++tp)
    Bx[tp].s = *(const short8*)&xT[jl * 1168 + w * PW + tp * 32 + g * 8];

  Frag ones;
  #pragma unroll
  for (int q = 0; q < 4; ++q) ones.u[q] = 0x3F803F80u;

  short* eW = eL + w * 3200;

  for (int it = 0; it < 3; ++it) {
    // ---------------- Y phase: b-MFMA -> exp2 -> e-write; then af-read -> y-MFMA ----------------
    f32x4 yC0 = {0.f, 0.f, 0.f, 0.f};
    f32x4 yC1 = {0.f, 0.f, 0.f, 0.f};
    if (it == 0) {                        // e == 1; split accumulator chains
      #pragma unroll
      for (int tp = 0; tp < 6; tp += 2) {
        yC0 = __builtin_amdgcn_mfma_f32_16x16x32_bf16(ones.s, Bx[tp].s,     yC0, 0, 0, 0);
        yC1 = __builtin_amdgcn_mfma_f32_16x16x32_bf16(ones.s, Bx[tp + 1].s, yC1, 0, 0, 0);
      }
    } else {
      Frag zf;                            // B-frag of Z: g 0,1 = Zh, g 2,3 = Zl
      {
        const float4 za = *(const float4*)&Zacc[jl * 8];
        const float4 zb = *(const float4*)&Zacc[jl * 8 + 4];
        const float zv[8] = {za.x, za.y, za.z, za.w, zb.x, zb.y, zb.z, zb.w};
        #pragma unroll
        for (int q = 0; q < 4; ++q) {
          unsigned h = pk_bf16(zv[2 * q], zv[2 * q + 1]);
          if (g >= 2) {
            const float l0 = zv[2 * q]     - bf_lo(h);
            const float l1 = zv[2 * q + 1] - bf_hi(h);
            h = pk_bf16(l0, l1);
          }
          zf.u[q] = h;
        }
      }
      #pragma unroll
      for (int t = 0; t < 12; ++t) {      // b = x.Z exact via hi/lo K-packing
        f32x4 bC = {0.f, 0.f, 0.f, 0.f};
        bC = __builtin_amdgcn_mfma_f32_16x16x32_bf16(Ax[t].s, zf.s, bC, 0, 0, 0);
        const float e0 = fexp2(bC[0]), e1 = fexp2(bC[1]);
        const float e2 = fexp2(bC[2]), e3 = fexp2(bC[3]);
        *(uint2*)&eW[jl * 200 + t * 16 + g * 4] =
            make_uint2(pk_bf16(e0, e1), pk_bf16(e2, e3));
      }
      #pragma unroll
      for (int tp = 0; tp < 6; tp += 2) { // y[j][k] (+ S at col 8), split chains
        Frag af0, af1;
        af0.s = *(const short8*)&eW[jl * 200 + tp * 32 + g * 8];
        af1.s = *(const short8*)&eW[jl * 200 + (tp + 1) * 32 + g * 8];
        yC0 = __builtin_amdgcn_mfma_f32_16x16x32_bf16(af0.s, Bx[tp].s,     yC0, 0, 0, 0);
        yC1 = __builtin_amdgcn_mfma_f32_16x16x32_bf16(af1.s, Bx[tp + 1].s, yC1, 0, 0, 0);
      }
    }
    #pragma unroll
    for (int r = 0; r < 4; ++r)           // D[j=g*4+r][k=jl]
      ypart[w * 272 + (g * 4 + r) * 17 + jl] = yC0[r] + yC1[r];
    __syncthreads();

    // ---- M (tid<160, one stage): combine -> s -> squash -> v -> (out | z -> Zacc) ----
    if (tid < 160) {
      const int j = tid >> 4, d = tid & 15;
      if (d < 9) {
        float s6 = 0.f;
        #pragma unroll
        for (int w6 = 0; w6 < NWV; ++w6) s6 += ypart[w6 * 272 + j * 17 + d];
        red[(d < 8) ? (j * 8 + d) : (80 + j)] = s6;
      }
      float wk[8];
      #pragma unroll
      for (int k = 0; k < 8; ++k) wk[k] = Wt[(j * 8 + k) * 18 + d];
      float s = 0.f;
      #pragma unroll
      for (int k = 0; k < 8; ++k) s = fmaf(wk[k], red[j * 8 + k], s);
      s *= frcp(red[80 + j]);
      const float sq = rsum_ror(s * s);
      // sq/((1+sq)*sqrt(sq+1e-9)) == sq * rcp(1+sq) * rsq(sq+1e-9)
      const float scal = sq * frcp(1.0f + sq) * frsq(sq + 1e-9f);
      const float v = s * scal;
      if (it == 2) {
        out[b * 160 + tid] = v;
      } else {
        float zk[8];
        #pragma unroll
        for (int k = 0; k < 8; ++k) zk[k] = rsum_shr(wk[k] * v);
        if (d == 15) {
          #pragma unroll
          for (int k = 0; k < 8; ++k)
            Zacc[j * 8 + k] = fmaf(zk[k], LOG2E, Zacc[j * 8 + k]);
        }
      }
    }
    if (it < 2) __syncthreads();
  }
}

extern "C" void kernel_launch(void* const* d_in, const int* in_sizes, int n_in,
                              void* d_out, int out_size, void* d_ws, size_t ws_size,
                              hipStream_t stream) {
  (void)in_sizes; (void)n_in; (void)out_size; (void)d_ws; (void)ws_size;
  const float* x = (const float*)d_in[0];
  const float* W = (const float*)d_in[1];
  float* out = (float*)d_out;

  const size_t smem = 88944;
  (void)hipFuncSetAttribute(reinterpret_cast<const void*>(caps_kernel),
                            hipFuncAttributeMaxDynamicSharedMemorySize, (int)smem);
  caps_kernel<<<B_, NT, smem, stream>>>(x, W, out);
}

// Round 16
// 13.232 us; speedup vs baseline: 1.2191x; 1.0226x over previous
//
#include <hip/hip_runtime.h>

#define B_   256
#define P_   1152
#define J_   10
#define NT   384      // 6 waves
#define NWV  6
#define PW   192      // p-rows per wave
#define XSTR 1176     // xT row stride (shorts)
#define LOG2E 1.44269504088896340736f

typedef __attribute__((ext_vector_type(8))) short short8;
typedef __attribute__((ext_vector_type(4))) float f32x4;

union Frag { short8 s; unsigned u[4]; };

__device__ __forceinline__ unsigned pk_bf16(float lo, float hi) {
  unsigned r;
  asm("v_cvt_pk_bf16_f32 %0, %1, %2" : "=v"(r) : "v"(lo), "v"(hi));
  return r;
}
__device__ __forceinline__ float bf_lo(unsigned u){ return __builtin_bit_cast(float, u << 16); }
__device__ __forceinline__ float bf_hi(unsigned u){ return __builtin_bit_cast(float, u & 0xffff0000u); }

// raw hardware transcendentals via builtins (backend-emitted, hazards handled)
__device__ __forceinline__ float fexp2(float x) { return __builtin_amdgcn_exp2f(x); }
__device__ __forceinline__ float frcp (float x) { return __builtin_amdgcn_rcpf(x); }
__device__ __forceinline__ float frsq (float x) { return __builtin_amdgcn_rsqf(x); }

template<int CTRL>
__device__ __forceinline__ float dpp_add(float v) {
  int s = __builtin_amdgcn_update_dpp(0, __builtin_bit_cast(int, v), CTRL, 0xF, 0xF, true);
  return v + __builtin_bit_cast(float, s);
}
__device__ __forceinline__ float rsum_shr(float v) {  // lane15 of each 16-row gets sum
  v = dpp_add<0x111>(v); v = dpp_add<0x112>(v);
  v = dpp_add<0x114>(v); v = dpp_add<0x118>(v);
  return v;
}
__device__ __forceinline__ float rsum_ror(float v) {  // all 16 lanes get the sum
  v = dpp_add<0x121>(v); v = dpp_add<0x122>(v);
  v = dpp_add<0x124>(v); v = dpp_add<0x128>(v);
  return v;
}

// LDS (dynamic, 72736 B):
//  xT    short[9][1176]    @0      x^T bf16 (rows 0-7 = x[k][p], row 8 = ones)
//                                  jl>=9 B-frag reads hit garbage -> only D cols
//                                  9-15 (never read by M). Proven safe (R12).
//  eL    short[6][16][200] @21168  per-wave e^T (bf16) [j][p_loc]
//  Wt    float[1440]       @59568  Wt[(j*8+k)*18+d] = W[j][d][k]
//  ypart float[6][272]     @65328  per-wave y tiles [16j][17]
//  red   float[92]         @71856  y[j*8+k], S at 80+j
//  Zacc  float[128]        @72224  cumulative z*log2e (80..127 zeroed: Z-frag
//                                  reads rows jl<=15)
__global__ __launch_bounds__(NT, 2) void caps_kernel(const float* __restrict__ x,
                                                     const float* __restrict__ Wg,
                                                     float* __restrict__ out) {
  extern __shared__ char smc[];
  short* xT    = (short*)smc;
  short* eL    = (short*)(smc + 21168);
  float* Wt    = (float*)(smc + 59568);
  float* ypart = (float*)(smc + 65328);
  float* red   = (float*)(smc + 71856);
  float* Zacc  = (float*)(smc + 72224);

  const int tid  = threadIdx.x;
  const int w    = tid >> 6;
  const int lane = tid & 63;
  const int b    = blockIdx.x;
  const int jl   = lane & 15;     // 16-col index
  const int g    = lane >> 4;     // 4-group

  // ---- single preamble phase: xT fill, ones row, Wt, Zacc zero, Ax; ONE barrier ----
  const float* xb = x + (size_t)b * (P_ * 8);
  for (int i = tid; i < 2304; i += NT) {
    float4 v4 = ((const float4*)xb)[i];
    const int p = i >> 1, k0 = (i & 1) * 4;
    xT[(k0 + 0) * XSTR + p] = (short)(pk_bf16(v4.x, v4.x) & 0xffff);
    xT[(k0 + 1) * XSTR + p] = (short)(pk_bf16(v4.y, v4.y) & 0xffff);
    xT[(k0 + 2) * XSTR + p] = (short)(pk_bf16(v4.z, v4.z) & 0xffff);
    xT[(k0 + 3) * XSTR + p] = (short)(pk_bf16(v4.w, v4.w) & 0xffff);
  }
  for (int p = tid; p < P_; p += NT) xT[8 * XSTR + p] = (short)0x3F80;
  for (int t = tid; t < 1280; t += NT) {
    const int j = t >> 7, d = (t >> 3) & 15, k = t & 7;
    Wt[(j * 8 + k) * 18 + d] = Wg[t];
  }
  if (tid < 128) Zacc[tid] = 0.f;

  Frag Ax[12];
  {
    const bool lop = (g & 1);
    #pragma unroll
    for (int t = 0; t < 12; ++t) {
      const float* xr = xb + ((size_t)(w * PW + t * 16 + jl)) * 8;
      const float4 a4 = ((const float4*)xr)[0];
      const float4 b4 = ((const float4*)xr)[1];
      const float xv[8] = {a4.x, a4.y, a4.z, a4.w, b4.x, b4.y, b4.z, b4.w};
      #pragma unroll
      for (int q = 0; q < 4; ++q) {
        unsigned h = pk_bf16(xv[2 * q], xv[2 * q + 1]);
        if (lop) {
          const float l0 = xv[2 * q]     - bf_lo(h);
          const float l1 = xv[2 * q + 1] - bf_hi(h);
          h = pk_bf16(l0, l1);
        }
        Ax[t].u[q] = h;
      }
    }
  }
  __syncthreads();

  // B-frags for y-MFMA (iteration-invariant)
  Frag Bx[6];
  #pragma unroll
  for (int tp = 0; tp < 6; ++tp)
    Bx[tp].s = *(const short8*)&xT[jl * XSTR + w * PW + tp * 32 + g * 8];

  Frag ones;
  #pragma unroll
  for (int q = 0; q < 4; ++q) ones.u[q] = 0x3F803F80u;

  short* eW = eL + w * 3200;

  for (int it = 0; it < 3; ++it) {
    // ---------------- Y phase: b-MFMA -> exp2 -> e-write; then af-read -> y-MFMA ----------------
    f32x4 yC0 = {0.f, 0.f, 0.f, 0.f};
    f32x4 yC1 = {0.f, 0.f, 0.f, 0.f};
    if (it == 0) {                        // e == 1; split accumulator chains
      #pragma unroll
      for (int tp = 0; tp < 6; tp += 2) {
        yC0 = __builtin_amdgcn_mfma_f32_16x16x32_bf16(ones.s, Bx[tp].s,     yC0, 0, 0, 0);
        yC1 = __builtin_amdgcn_mfma_f32_16x16x32_bf16(ones.s, Bx[tp + 1].s, yC1, 0, 0, 0);
      }
    } else {
      Frag zf;                            // B-frag of Z: g 0,1 = Zh, g 2,3 = Zl
      {
        const float4 za = *(const float4*)&Zacc[jl * 8];
        const float4 zb = *(const float4*)&Zacc[jl * 8 + 4];
        const float zv[8] = {za.x, za.y, za.z, za.w, zb.x, zb.y, zb.z, zb.w};
        #pragma unroll
        for (int q = 0; q < 4; ++q) {
          unsigned h = pk_bf16(zv[2 * q], zv[2 * q + 1]);
          if (g >= 2) {
            const float l0 = zv[2 * q]     - bf_lo(h);
            const float l1 = zv[2 * q + 1] - bf_hi(h);
            h = pk_bf16(l0, l1);
          }
          zf.u[q] = h;
        }
      }
      #pragma unroll
      for (int t = 0; t < 12; ++t) {      // b = x.Z exact via hi/lo K-packing
        f32x4 bC = {0.f, 0.f, 0.f, 0.f};
        bC = __builtin_amdgcn_mfma_f32_16x16x32_bf16(Ax[t].s, zf.s, bC, 0, 0, 0);
        const float e0 = fexp2(bC[0]), e1 = fexp2(bC[1]);
        const float e2 = fexp2(bC[2]), e3 = fexp2(bC[3]);
        *(uint2*)&eW[jl * 200 + t * 16 + g * 4] =
            make_uint2(pk_bf16(e0, e1), pk_bf16(e2, e3));
      }
      #pragma unroll
      for (int tp = 0; tp < 6; tp += 2) { // y[j][k] (+ S at col 8), split chains
        Frag af0, af1;
        af0.s = *(const short8*)&eW[jl * 200 + tp * 32 + g * 8];
        af1.s = *(const short8*)&eW[jl * 200 + (tp + 1) * 32 + g * 8];
        yC0 = __builtin_amdgcn_mfma_f32_16x16x32_bf16(af0.s, Bx[tp].s,     yC0, 0, 0, 0);
        yC1 = __builtin_amdgcn_mfma_f32_16x16x32_bf16(af1.s, Bx[tp + 1].s, yC1, 0, 0, 0);
      }
    }
    #pragma unroll
    for (int r = 0; r < 4; ++r)           // D[j=g*4+r][k=jl]
      ypart[w * 272 + (g * 4 + r) * 17 + jl] = yC0[r] + yC1[r];
    __syncthreads();

    // ---- M (tid<160, one stage): combine -> s -> squash -> v -> (out | z -> Zacc) ----
    if (tid < 160) {
      const int j = tid >> 4, d = tid & 15;
      if (d < 9) {
        float s6 = 0.f;
        #pragma unroll
        for (int w6 = 0; w6 < NWV; ++w6) s6 += ypart[w6 * 272 + j * 17 + d];
        red[(d < 8) ? (j * 8 + d) : (80 + j)] = s6;
      }
      float wk[8];
      #pragma unroll
      for (int k = 0; k < 8; ++k) wk[k] = Wt[(j * 8 + k) * 18 + d];
      float s = 0.f;
      #pragma unroll
      for (int k = 0; k < 8; ++k) s = fmaf(wk[k], red[j * 8 + k], s);
      s *= frcp(red[80 + j]);
      const float sq = rsum_ror(s * s);
      // sq/((1+sq)*sqrt(sq+1e-9)) == sq * rcp(1+sq) * rsq(sq+1e-9)
      const float scal = sq * frcp(1.0f + sq) * frsq(sq + 1e-9f);
      const float v = s * scal;
      if (it == 2) {
        out[b * 160 + tid] = v;
      } else {
        float zk[8];
        #pragma unroll
        for (int k = 0; k < 8; ++k) zk[k] = rsum_shr(wk[k] * v);
        if (d == 15) {
          #pragma unroll
          for (int k = 0; k < 8; ++k)
            Zacc[j * 8 + k] = fmaf(zk[k], LOG2E, Zacc[j * 8 + k]);
        }
      }
    }
    if (it < 2) __syncthreads();
  }
}

extern "C" void kernel_launch(void* const* d_in, const int* in_sizes, int n_in,
                              void* d_out, int out_size, void* d_ws, size_t ws_size,
                              hipStream_t stream) {
  (void)in_sizes; (void)n_in; (void)out_size; (void)d_ws; (void)ws_size;
  const float* x = (const float*)d_in[0];
  const float* W = (const float*)d_in[1];
  float* out = (float*)d_out;

  const size_t smem = 72736;
  (void)hipFuncSetAttribute(reinterpret_cast<const void*>(caps_kernel),
                            hipFuncAttributeMaxDynamicSharedMemorySize, (int)smem);
  caps_kernel<<<B_, NT, smem, stream>>>(x, W, out);
}